// Round 2
// baseline (3429.049 us; speedup 1.0000x reference)
//
#include <hip/hip_runtime.h>
#include <hip/hip_bf16.h>
#include <math.h>

// Problem constants (fixed by setup_inputs)
#define C_DIM 192
#define NH 6
#define HD 32
#define L_WIN 144             // 2*6*12
#define NWIN 960              // 4*16*15
#define MROWS (NWIN * L_WIN)  // 138240 window tokens
#define NTOK 131040           // 8*91*180 real tokens
#define Z_ 8
#define H_ 91
#define W_ 180
#define HP_ 96

// Workspace layout (bytes), peak 212,336,640:
//   xw    bf16 MROWS*192 = 53,084,160   @ 0            (dead after qkv gemm)
//   qkv   bf16 MROWS*576 = 159,252,480  @ 53,084,160   (dead after attn)
//   attno bf16 MROWS*192 = 53,084,160   @ 0  (reuse)   (dead after proj)
//   hb    bf16 NTOK*768  = 201,277,440  @ 0  (reuse)
//   x1    fp32 NTOK*192  -> stored in d_out (residual buffer)
#define WS_REQUIRED 212336640ull

__device__ __forceinline__ int win_token_to_tok(int r) {
    int n = r / L_WIN, l = r - n * L_WIN;
    int wz = n / 240;
    int rem = n - wz * 240;
    int wh = rem / 15;
    int ww = rem - wh * 15;
    int iz = l / 72;
    int r2 = l - iz * 72;
    int ih = r2 / 12;
    int iw = r2 - ih * 12;
    int z = wz * 2 + iz;
    int h = wh * 6 + ih;
    int w = ww * 12 + iw;
    int zp = z + 1; if (zp >= Z_) zp -= Z_;
    int hp = h + 3; if (hp >= HP_) hp -= HP_;
    int wp = w + 6; if (wp >= W_) wp -= W_;
    if (hp >= H_) return -1;
    return (zp * H_ + hp) * W_ + wp;
}

// ---------------- Kernel 1: gather (pad+roll+partition) + LayerNorm(norm1) ----
__global__ __launch_bounds__(256)
void gather_ln_kernel(const float* __restrict__ x, const float* __restrict__ g,
                      const float* __restrict__ b, __hip_bfloat16* __restrict__ xw) {
    int wave = threadIdx.x >> 6;
    int lane = threadIdx.x & 63;
    int r = blockIdx.x * 4 + wave;
    if (r >= MROWS) return;
    int tok = win_token_to_tok(r);
    float v0 = 0.f, v1 = 0.f, v2 = 0.f;
    if (tok >= 0) {
        const float* p = x + (size_t)tok * C_DIM;
        v0 = p[lane]; v1 = p[lane + 64]; v2 = p[lane + 128];
    }
    float s = v0 + v1 + v2;
    float sq = v0 * v0 + v1 * v1 + v2 * v2;
    #pragma unroll
    for (int off = 32; off; off >>= 1) {
        s += __shfl_xor(s, off);
        sq += __shfl_xor(sq, off);
    }
    float m = s * (1.f / 192.f);
    float var = sq * (1.f / 192.f) - m * m;
    float inv = rsqrtf(var + 1e-5f);
    __hip_bfloat16* o = xw + (size_t)r * C_DIM;
    o[lane]       = __float2bfloat16((v0 - m) * inv * g[lane]       + b[lane]);
    o[lane + 64]  = __float2bfloat16((v1 - m) * inv * g[lane + 64]  + b[lane + 64]);
    o[lane + 128] = __float2bfloat16((v2 - m) * inv * g[lane + 128] + b[lane + 128]);
}

// ---------------- Tiled GEMM: C[M,N] = A[M,K] @ B[N,K]^T (+epilogue) ----------
// MODE 0: qkv  -> Obf = bf16(acc + bias)
// MODE 1: proj -> Cout[d] = acc + bias + X[d]  (scatter through window map)
// MODE 2: fc1  -> Obf = bf16(gelu(acc + bias))
template<int MODE, bool ABF16>
__global__ __launch_bounds__(256)
void gemm64(const void* __restrict__ Av, const float* __restrict__ B,
            const float* __restrict__ bias, float* __restrict__ Cout,
            const float* __restrict__ X, __hip_bfloat16* __restrict__ Obf,
            int M, int N, int K) {
    __shared__ float As[16][65];
    __shared__ float Bs[16][65];
    int t = threadIdx.x;
    int tx = t & 15, ty = t >> 4;
    int row0 = blockIdx.x * 64, col0 = blockIdx.y * 64;
    int lr = t >> 2, lc = (t & 3) * 4;
    int ar = row0 + lr;
    int br = col0 + lr;
    float acc[4][4] = {};

    for (int k0 = 0; k0 < K; k0 += 16) {
        float a0, a1, a2, a3;
        if (ar < M) {
            if constexpr (ABF16) {
                const __hip_bfloat16* A = (const __hip_bfloat16*)Av;
                uint2 u = *(const uint2*)(A + (size_t)ar * K + k0 + lc);
                a0 = __uint_as_float(u.x << 16);
                a1 = __uint_as_float(u.x & 0xffff0000u);
                a2 = __uint_as_float(u.y << 16);
                a3 = __uint_as_float(u.y & 0xffff0000u);
            } else {
                const float* A = (const float*)Av;
                float4 f = *(const float4*)(A + (size_t)ar * K + k0 + lc);
                a0 = f.x; a1 = f.y; a2 = f.z; a3 = f.w;
            }
        } else { a0 = a1 = a2 = a3 = 0.f; }
        As[lc + 0][lr] = a0; As[lc + 1][lr] = a1;
        As[lc + 2][lr] = a2; As[lc + 3][lr] = a3;

        float4 bf = *(const float4*)(B + (size_t)br * K + k0 + lc);
        Bs[lc + 0][lr] = bf.x; Bs[lc + 1][lr] = bf.y;
        Bs[lc + 2][lr] = bf.z; Bs[lc + 3][lr] = bf.w;
        __syncthreads();

        #pragma unroll
        for (int kk = 0; kk < 16; ++kk) {
            float a[4], bb[4];
            #pragma unroll
            for (int i = 0; i < 4; i++) a[i] = As[kk][ty * 4 + i];
            #pragma unroll
            for (int j = 0; j < 4; j++) bb[j] = Bs[kk][tx * 4 + j];
            #pragma unroll
            for (int i = 0; i < 4; i++)
                #pragma unroll
                for (int j = 0; j < 4; j++)
                    acc[i][j] = fmaf(a[i], bb[j], acc[i][j]);
        }
        __syncthreads();
    }

    #pragma unroll
    for (int i = 0; i < 4; i++) {
        int r = row0 + ty * 4 + i;
        if (r >= M) continue;
        int d = -1;
        if constexpr (MODE == 1) {
            d = win_token_to_tok(r);
            if (d < 0) continue;
        }
        #pragma unroll
        for (int j = 0; j < 4; j++) {
            int n = col0 + tx * 4 + j;
            float v = acc[i][j] + bias[n];
            if constexpr (MODE == 0) {
                Obf[(size_t)r * N + n] = __float2bfloat16(v);
            } else if constexpr (MODE == 1) {
                Cout[(size_t)d * C_DIM + n] = v + X[(size_t)d * C_DIM + n];
            } else {
                float gl = 0.5f * v * (1.f + erff(v * 0.70710678118654752f));
                Obf[(size_t)r * N + n] = __float2bfloat16(gl);
            }
        }
    }
}

// ---------------- Kernel 3: windowed attention, one block per (window, head) --
__global__ __launch_bounds__(256)
void attn_kernel(const __hip_bfloat16* __restrict__ qkv,
                 __hip_bfloat16* __restrict__ out) {
    __shared__ float Qs[L_WIN][HD + 1];
    __shared__ float Ks[L_WIN][HD + 1];
    __shared__ float Vs[L_WIN][HD + 1];
    __shared__ float Ps[4][L_WIN];
    int blk = blockIdx.x;
    int n = blk / NH, head = blk - n * NH;
    const __hip_bfloat16* base = qkv + (size_t)n * L_WIN * 576 + head * HD;
    const float scale = 0.17677669529663687f;  // 1/sqrt(32)
    for (int idx = threadIdx.x; idx < L_WIN * HD; idx += 256) {
        int l = idx >> 5, c = idx & 31;
        Qs[l][c] = __bfloat162float(base[l * 576 + c]) * scale;
        Ks[l][c] = __bfloat162float(base[l * 576 + 192 + c]);
        Vs[l][c] = __bfloat162float(base[l * 576 + 384 + c]);
    }
    __syncthreads();
    int wave = threadIdx.x >> 6, lane = threadIdx.x & 63;
    for (int l = wave; l < L_WIN; l += 4) {
        float s0 = 0.f, s1 = 0.f, s2 = 0.f;
        #pragma unroll
        for (int k = 0; k < HD; k++) {
            float q = Qs[l][k];
            s0 = fmaf(q, Ks[lane][k], s0);
            s1 = fmaf(q, Ks[lane + 64][k], s1);
            if (lane < 16) s2 = fmaf(q, Ks[lane + 128][k], s2);
        }
        float mx = fmaxf(s0, s1);
        if (lane < 16) mx = fmaxf(mx, s2);
        #pragma unroll
        for (int off = 32; off; off >>= 1) mx = fmaxf(mx, __shfl_xor(mx, off));
        float e0 = expf(s0 - mx), e1 = expf(s1 - mx);
        float e2 = (lane < 16) ? expf(s2 - mx) : 0.f;
        float ssum = e0 + e1 + e2;
        #pragma unroll
        for (int off = 32; off; off >>= 1) ssum += __shfl_xor(ssum, off);
        float rs = 1.f / ssum;
        Ps[wave][lane] = e0 * rs;
        Ps[wave][lane + 64] = e1 * rs;
        if (lane < 16) Ps[wave][lane + 128] = e2 * rs;
        asm volatile("s_waitcnt lgkmcnt(0)" ::: "memory");
        int c = lane & 31, half = lane >> 5;
        float o = 0.f;
        int j0 = half * 72;
        for (int j = j0; j < j0 + 72; ++j) o = fmaf(Ps[wave][j], Vs[j][c], o);
        o += __shfl_xor(o, 32);
        if (half == 0)
            out[((size_t)n * L_WIN + l) * C_DIM + head * HD + c] =
                __float2bfloat16(o);
    }
}

// ---------------- Kernel 4: fc2 + bias + LayerNorm(norm2) + residual ----------
// Per block: 64 rows x all 192 cols. io holds x1 on entry, final output on exit.
__global__ __launch_bounds__(256)
void fc2_ln_kernel(const __hip_bfloat16* __restrict__ hb,
                   const float* __restrict__ B, const float* __restrict__ bias,
                   const float* __restrict__ g, const float* __restrict__ bb2,
                   float* __restrict__ io) {
    __shared__ float As[16][65];
    __shared__ float Bs[16][193];
    int t = threadIdx.x;
    int tx = t & 15, ty = t >> 4;
    int row0 = blockIdx.x * 64;
    int lr = t >> 2, lc = (t & 3) * 4;
    int ar = row0 + lr;
    float acc[4][12] = {};

    for (int k0 = 0; k0 < 768; k0 += 16) {
        float a0 = 0.f, a1 = 0.f, a2 = 0.f, a3 = 0.f;
        if (ar < NTOK) {
            uint2 u = *(const uint2*)(hb + (size_t)ar * 768 + k0 + lc);
            a0 = __uint_as_float(u.x << 16);
            a1 = __uint_as_float(u.x & 0xffff0000u);
            a2 = __uint_as_float(u.y << 16);
            a3 = __uint_as_float(u.y & 0xffff0000u);
        }
        As[lc + 0][lr] = a0; As[lc + 1][lr] = a1;
        As[lc + 2][lr] = a2; As[lc + 3][lr] = a3;
        for (int rr = lr; rr < 192; rr += 64) {
            float4 bf = *(const float4*)(B + (size_t)rr * 768 + k0 + lc);
            Bs[lc + 0][rr] = bf.x; Bs[lc + 1][rr] = bf.y;
            Bs[lc + 2][rr] = bf.z; Bs[lc + 3][rr] = bf.w;
        }
        __syncthreads();
        #pragma unroll
        for (int kk = 0; kk < 16; ++kk) {
            float a[4];
            #pragma unroll
            for (int i = 0; i < 4; i++) a[i] = As[kk][ty * 4 + i];
            #pragma unroll
            for (int tile = 0; tile < 3; tile++) {
                float bv[4];
                #pragma unroll
                for (int j = 0; j < 4; j++) bv[j] = Bs[kk][tile * 64 + tx * 4 + j];
                #pragma unroll
                for (int i = 0; i < 4; i++)
                    #pragma unroll
                    for (int j = 0; j < 4; j++)
                        acc[i][tile * 4 + j] = fmaf(a[i], bv[j], acc[i][tile * 4 + j]);
            }
        }
        __syncthreads();
    }

    #pragma unroll
    for (int i = 0; i < 4; i++) {
        int r = row0 + ty * 4 + i;
        float v[12];
        float s = 0.f, sq = 0.f;
        #pragma unroll
        for (int tile = 0; tile < 3; tile++)
            #pragma unroll
            for (int j = 0; j < 4; j++) {
                int col = tile * 64 + tx * 4 + j;
                float h = acc[i][tile * 4 + j] + bias[col];
                v[tile * 4 + j] = h;
                s += h; sq += h * h;
            }
        #pragma unroll
        for (int off = 8; off; off >>= 1) {
            s += __shfl_xor(s, off);
            sq += __shfl_xor(sq, off);
        }
        float m = s * (1.f / 192.f);
        float var = sq * (1.f / 192.f) - m * m;
        float inv = rsqrtf(var + 1e-5f);
        if (r < NTOK) {
            #pragma unroll
            for (int tile = 0; tile < 3; tile++)
                #pragma unroll
                for (int j = 0; j < 4; j++) {
                    int col = tile * 64 + tx * 4 + j;
                    size_t idx = (size_t)r * C_DIM + col;
                    io[idx] = io[idx] + (v[tile * 4 + j] - m) * inv * g[col] + bb2[col];
                }
        }
    }
}

extern "C" void kernel_launch(void* const* d_in, const int* in_sizes, int n_in,
                              void* d_out, int out_size, void* d_ws, size_t ws_size,
                              hipStream_t stream) {
    const float* x      = (const float*)d_in[0];
    const float* n1g    = (const float*)d_in[1];
    const float* n1b    = (const float*)d_in[2];
    const float* qkv_w  = (const float*)d_in[3];
    const float* qkv_b  = (const float*)d_in[4];
    const float* proj_w = (const float*)d_in[5];
    const float* proj_b = (const float*)d_in[6];
    const float* n2g    = (const float*)d_in[7];
    const float* n2b    = (const float*)d_in[8];
    const float* fc1_w  = (const float*)d_in[9];
    const float* fc1_b  = (const float*)d_in[10];
    const float* fc2_w  = (const float*)d_in[11];
    const float* fc2_b  = (const float*)d_in[12];
    float* out = (float*)d_out;

    if (ws_size < WS_REQUIRED) return;  // diagnostic: clean fail instead of OOB abort

    char* ws = (char*)d_ws;
    __hip_bfloat16* xw    = (__hip_bfloat16*)(ws);
    __hip_bfloat16* qkvb  = (__hip_bfloat16*)(ws + 53084160);
    __hip_bfloat16* attno = (__hip_bfloat16*)(ws);
    __hip_bfloat16* hb    = (__hip_bfloat16*)(ws);
    float* x1 = out;  // residual buffer lives in d_out

    gather_ln_kernel<<<MROWS / 4, 256, 0, stream>>>(x, n1g, n1b, xw);

    gemm64<0, true><<<dim3(MROWS / 64, 576 / 64), 256, 0, stream>>>(
        xw, qkv_w, qkv_b, nullptr, nullptr, qkvb, MROWS, 576, 192);

    attn_kernel<<<NWIN * NH, 256, 0, stream>>>(qkvb, attno);

    gemm64<1, true><<<dim3(MROWS / 64, 192 / 64), 256, 0, stream>>>(
        attno, proj_w, proj_b, x1, x, nullptr, MROWS, 192, 192);

    gemm64<2, false><<<dim3((NTOK + 63) / 64, 768 / 64), 256, 0, stream>>>(
        x1, fc1_w, fc1_b, nullptr, nullptr, hb, NTOK, 768, 192);

    fc2_ln_kernel<<<(NTOK + 63) / 64, 256, 0, stream>>>(
        hb, fc2_w, fc2_b, n2g, n2b, x1);
}

// Round 3
// 668.956 us; speedup vs baseline: 5.1260x; 5.1260x over previous
//
#include <hip/hip_runtime.h>
#include <hip/hip_bf16.h>
#include <math.h>

#define C_DIM 192
#define NH 6
#define HD 32
#define L_WIN 144
#define NWIN 960
#define MROWS (NWIN * L_WIN)   // 138240
#define NTOK 131040            // 8*91*180
#define Z_ 8
#define H_ 91
#define W_ 180
#define HP_ 96
#define WS_REQUIRED 212336640ull

typedef __attribute__((ext_vector_type(8))) short bf16x8;
typedef __attribute__((ext_vector_type(4))) float f32x4;

__device__ __forceinline__ short f2bf(float f) {
    __hip_bfloat16 h = __float2bfloat16(f);
    union { __hip_bfloat16 h; short s; } u; u.h = h; return u.s;
}
__device__ __forceinline__ float bf2f(short s) {
    return __uint_as_float(((unsigned int)(unsigned short)s) << 16);
}

__device__ __forceinline__ int win_token_to_tok(int r) {
    int n = r / L_WIN, l = r - n * L_WIN;
    int wz = n / 240;
    int rem = n - wz * 240;
    int wh = rem / 15;
    int ww = rem - wh * 15;
    int iz = l / 72;
    int r2 = l - iz * 72;
    int ih = r2 / 12;
    int iw = r2 - ih * 12;
    int z = wz * 2 + iz;
    int h = wh * 6 + ih;
    int w = ww * 12 + iw;
    int zp = z + 1; if (zp >= Z_) zp -= Z_;
    int hp = h + 3; if (hp >= HP_) hp -= HP_;
    int wp = w + 6; if (wp >= W_) wp -= W_;
    if (hp >= H_) return -1;
    return (zp * H_ + hp) * W_ + wp;
}

// ---------------- Kernel 1: gather (pad+roll+partition) + LayerNorm(norm1) ----
__global__ __launch_bounds__(256)
void gather_ln_kernel(const float* __restrict__ x, const float* __restrict__ g,
                      const float* __restrict__ b, short* __restrict__ xw) {
    int wave = threadIdx.x >> 6;
    int lane = threadIdx.x & 63;
    int r = blockIdx.x * 4 + wave;
    if (r >= MROWS) return;
    int tok = win_token_to_tok(r);
    float v0 = 0.f, v1 = 0.f, v2 = 0.f;
    if (tok >= 0) {
        const float* p = x + (size_t)tok * C_DIM;
        v0 = p[lane]; v1 = p[lane + 64]; v2 = p[lane + 128];
    }
    float s = v0 + v1 + v2;
    float sq = v0 * v0 + v1 * v1 + v2 * v2;
    #pragma unroll
    for (int off = 32; off; off >>= 1) {
        s += __shfl_xor(s, off);
        sq += __shfl_xor(sq, off);
    }
    float m = s * (1.f / 192.f);
    float var = sq * (1.f / 192.f) - m * m;
    float inv = rsqrtf(var + 1e-5f);
    short* o = xw + (size_t)r * C_DIM;
    o[lane]       = f2bf((v0 - m) * inv * g[lane]       + b[lane]);
    o[lane + 64]  = f2bf((v1 - m) * inv * g[lane + 64]  + b[lane + 64]);
    o[lane + 128] = f2bf((v2 - m) * inv * g[lane + 128] + b[lane + 128]);
}

// ---------------- MFMA GEMM: C[M,N] = A[M,K] @ B[N,K]^T (+epilogue) -----------
// MODE 0: qkv  -> Obf = bf16(acc + bias)
// MODE 1: proj -> Cf[d] = acc + bias + X[d]  (scatter through window map)
// MODE 2: fc1  -> Obf = bf16(gelu(acc + bias))
// BM=128, BN=64, BK=32. 4 waves in 2x2; each wave 4x2 frags of 16x16.
template<int MODE, bool A_FP32, int N>
__global__ __launch_bounds__(256)
void gemm_mfma(const void* __restrict__ Av, const float* __restrict__ Bw,
               const float* __restrict__ bias, short* __restrict__ Obf,
               float* __restrict__ Cf, const float* __restrict__ X,
               int M, int K) {
    __shared__ __align__(16) short As[128][40];
    __shared__ __align__(16) short Bs[64][40];
    int t = threadIdx.x;
    int w = t >> 6, l = t & 63, g = l >> 4, c = l & 15;
    int row0 = blockIdx.y * 128, col0 = blockIdx.x * 64;
    int wr = (w >> 1) * 64, wc = (w & 1) * 32;
    f32x4 acc[4][2] = {};

    for (int k0 = 0; k0 < K; k0 += 32) {
        #pragma unroll
        for (int i = 0; i < 2; i++) {
            int ch = t + i * 256;
            int r = ch >> 2, cc = (ch & 3) * 8;
            int gr = row0 + r;
            bf16x8 v = {};
            if (gr < M) {
                if constexpr (A_FP32) {
                    const float* p = (const float*)Av + (size_t)gr * K + k0 + cc;
                    float4 f0 = *(const float4*)p;
                    float4 f1 = *(const float4*)(p + 4);
                    v[0] = f2bf(f0.x); v[1] = f2bf(f0.y); v[2] = f2bf(f0.z); v[3] = f2bf(f0.w);
                    v[4] = f2bf(f1.x); v[5] = f2bf(f1.y); v[6] = f2bf(f1.z); v[7] = f2bf(f1.w);
                } else {
                    v = *(const bf16x8*)((const short*)Av + (size_t)gr * K + k0 + cc);
                }
            }
            *(bf16x8*)(&As[r][cc]) = v;
        }
        {
            int r = t >> 2, cc = (t & 3) * 8;
            const float* p = Bw + (size_t)(col0 + r) * K + k0 + cc;
            float4 f0 = *(const float4*)p;
            float4 f1 = *(const float4*)(p + 4);
            bf16x8 v;
            v[0] = f2bf(f0.x); v[1] = f2bf(f0.y); v[2] = f2bf(f0.z); v[3] = f2bf(f0.w);
            v[4] = f2bf(f1.x); v[5] = f2bf(f1.y); v[6] = f2bf(f1.z); v[7] = f2bf(f1.w);
            *(bf16x8*)(&Bs[r][cc]) = v;
        }
        __syncthreads();
        bf16x8 af[4], bfr[2];
        #pragma unroll
        for (int m = 0; m < 4; m++) af[m] = *(const bf16x8*)(&As[wr + 16 * m + c][g * 8]);
        #pragma unroll
        for (int n = 0; n < 2; n++) bfr[n] = *(const bf16x8*)(&Bs[wc + 16 * n + c][g * 8]);
        #pragma unroll
        for (int m = 0; m < 4; m++)
            #pragma unroll
            for (int n = 0; n < 2; n++)
                acc[m][n] = __builtin_amdgcn_mfma_f32_16x16x32_bf16(af[m], bfr[n], acc[m][n], 0, 0, 0);
        __syncthreads();
    }

    #pragma unroll
    for (int m = 0; m < 4; m++) {
        #pragma unroll
        for (int reg = 0; reg < 4; reg++) {
            int r = row0 + wr + 16 * m + 4 * g + reg;
            if (r >= M) continue;
            int d = -1;
            if constexpr (MODE == 1) {
                d = win_token_to_tok(r);
                if (d < 0) continue;
            }
            #pragma unroll
            for (int n = 0; n < 2; n++) {
                int col = col0 + wc + 16 * n + c;
                float v = acc[m][n][reg] + bias[col];
                if constexpr (MODE == 0) {
                    Obf[(size_t)r * N + col] = f2bf(v);
                } else if constexpr (MODE == 1) {
                    Cf[(size_t)d * C_DIM + col] = v + X[(size_t)d * C_DIM + col];
                } else {
                    float gl = 0.5f * v * (1.f + erff(v * 0.7071067811865475f));
                    Obf[(size_t)r * N + col] = f2bf(gl);
                }
            }
        }
    }
}

// ---------------- MFMA attention: one block per (window, head) ----------------
__global__ __launch_bounds__(256)
void attn_mfma(const short* __restrict__ qkv, short* __restrict__ attno) {
    __shared__ __align__(16) short Vt[32][168];     // V transposed, kv-padded to 160
    __shared__ __align__(16) short Pl[4][16][168];  // per-wave P tile
    int blk = blockIdx.x;
    int win = blk / NH, head = blk - win * NH;
    int t = threadIdx.x, w = t >> 6, l = t & 63, g = l >> 4, c = l & 15;
    const short* base = qkv + (size_t)win * L_WIN * 576 + head * HD;

    // stage V transposed (rows kv=0..143), zero the kv pad
    for (int ch = t; ch < 576; ch += 256) {
        int kv = ch >> 2, cc = (ch & 3) * 8;
        bf16x8 v = *(const bf16x8*)(base + kv * 576 + 384 + cc);
        #pragma unroll
        for (int j = 0; j < 8; j++) Vt[cc + j][kv] = v[j];
    }
    for (int i = t; i < 32 * 24; i += 256) Vt[i / 24][144 + i % 24] = 0;
    for (int i = l; i < 16 * 24; i += 64) Pl[w][i / 24][144 + i % 24] = 0;
    __syncthreads();

    // hoist K fragments (B-operand): lane reads K[16n+c][g*8 .. g*8+7]
    bf16x8 kf[9];
    #pragma unroll
    for (int n = 0; n < 9; n++)
        kf[n] = *(const bf16x8*)(base + (16 * n + c) * 576 + 192 + g * 8);

    const float scale = 0.17677669529663687f;
    for (int m = w; m < 9; m += 4) {
        bf16x8 qf = *(const bf16x8*)(base + (16 * m + c) * 576 + g * 8);
        f32x4 s[9];
        #pragma unroll
        for (int n = 0; n < 9; n++) {
            f32x4 z = {};
            s[n] = __builtin_amdgcn_mfma_f32_16x16x32_bf16(qf, kf[n], z, 0, 0, 0);
        }
        // softmax over kv (per q-row = 4g+reg): in-lane over n, cross-lane over c
        float mx[4], sm[4], rs[4];
        #pragma unroll
        for (int reg = 0; reg < 4; reg++) {
            float v = -1e30f;
            #pragma unroll
            for (int n = 0; n < 9; n++) { s[n][reg] *= scale; v = fmaxf(v, s[n][reg]); }
            #pragma unroll
            for (int off = 1; off <= 8; off <<= 1) v = fmaxf(v, __shfl_xor(v, off));
            mx[reg] = v;
        }
        #pragma unroll
        for (int reg = 0; reg < 4; reg++) {
            float acc = 0.f;
            #pragma unroll
            for (int n = 0; n < 9; n++) {
                float e = expf(s[n][reg] - mx[reg]);
                s[n][reg] = e;
                acc += e;
            }
            #pragma unroll
            for (int off = 1; off <= 8; off <<= 1) acc += __shfl_xor(acc, off);
            sm[reg] = acc;
            rs[reg] = 1.f / acc;
        }
        // write P (unnormalized, <=1) to per-wave LDS tile
        #pragma unroll
        for (int n = 0; n < 9; n++)
            #pragma unroll
            for (int reg = 0; reg < 4; reg++)
                Pl[w][4 * g + reg][16 * n + c] = f2bf(s[n][reg]);
        asm volatile("s_waitcnt lgkmcnt(0)" ::: "memory");
        // PV: O[16x32] over 5 k-steps of 32 (kv padded with zeros)
        f32x4 o[2] = {};
        #pragma unroll
        for (int ks = 0; ks < 5; ks++) {
            bf16x8 pa = *(const bf16x8*)(&Pl[w][c][32 * ks + 8 * g]);
            #pragma unroll
            for (int df = 0; df < 2; df++) {
                bf16x8 vb = *(const bf16x8*)(&Vt[16 * df + c][32 * ks + 8 * g]);
                o[df] = __builtin_amdgcn_mfma_f32_16x16x32_bf16(pa, vb, o[df], 0, 0, 0);
            }
        }
        #pragma unroll
        for (int df = 0; df < 2; df++)
            #pragma unroll
            for (int reg = 0; reg < 4; reg++)
                attno[(size_t)(win * L_WIN + 16 * m + 4 * g + reg) * C_DIM +
                      head * HD + 16 * df + c] = f2bf(o[df][reg] * rs[reg]);
    }
}

// ---------------- fc2 (MFMA) + bias + LayerNorm(norm2) + residual -------------
// BM=64, BN=192 (full row). wave w owns cols 48w..48w+47 (3 n-frags), 4 m-frags.
__global__ __launch_bounds__(256)
void fc2_ln_mfma(const short* __restrict__ hb, const float* __restrict__ Bw,
                 const float* __restrict__ bias, const float* __restrict__ g2,
                 const float* __restrict__ b2, float* __restrict__ io) {
    __shared__ __align__(16) short As[64][40];
    __shared__ __align__(16) short Bs[192][40];
    __shared__ float reds[64][4];
    __shared__ float redq[64][4];
    int t = threadIdx.x;
    int w = t >> 6, l = t & 63, g = l >> 4, c = l & 15;
    int row0 = blockIdx.x * 64;
    f32x4 acc[4][3] = {};

    for (int k0 = 0; k0 < 768; k0 += 32) {
        {
            int r = t >> 2, cc = (t & 3) * 8;
            int gr = row0 + r;
            bf16x8 v = {};
            if (gr < NTOK) v = *(const bf16x8*)(hb + (size_t)gr * 768 + k0 + cc);
            *(bf16x8*)(&As[r][cc]) = v;
        }
        #pragma unroll
        for (int i = 0; i < 3; i++) {
            int ch = t + i * 256;
            int r = ch >> 2, cc = (ch & 3) * 8;
            const float* p = Bw + (size_t)r * 768 + k0 + cc;
            float4 f0 = *(const float4*)p;
            float4 f1 = *(const float4*)(p + 4);
            bf16x8 v;
            v[0] = f2bf(f0.x); v[1] = f2bf(f0.y); v[2] = f2bf(f0.z); v[3] = f2bf(f0.w);
            v[4] = f2bf(f1.x); v[5] = f2bf(f1.y); v[6] = f2bf(f1.z); v[7] = f2bf(f1.w);
            *(bf16x8*)(&Bs[r][cc]) = v;
        }
        __syncthreads();
        bf16x8 af[4], bfr[3];
        #pragma unroll
        for (int m = 0; m < 4; m++) af[m] = *(const bf16x8*)(&As[16 * m + c][g * 8]);
        #pragma unroll
        for (int n = 0; n < 3; n++) bfr[n] = *(const bf16x8*)(&Bs[48 * w + 16 * n + c][g * 8]);
        #pragma unroll
        for (int m = 0; m < 4; m++)
            #pragma unroll
            for (int n = 0; n < 3; n++)
                acc[m][n] = __builtin_amdgcn_mfma_f32_16x16x32_bf16(af[m], bfr[n], acc[m][n], 0, 0, 0);
        __syncthreads();
    }

    // add bias; per-row partial sums (48 cols per wave) -> LDS
    #pragma unroll
    for (int m = 0; m < 4; m++) {
        #pragma unroll
        for (int reg = 0; reg < 4; reg++) {
            float s = 0.f, sq = 0.f;
            #pragma unroll
            for (int n = 0; n < 3; n++) {
                int col = 48 * w + 16 * n + c;
                float h = acc[m][n][reg] + bias[col];
                acc[m][n][reg] = h;
                s += h; sq += h * h;
            }
            #pragma unroll
            for (int off = 1; off <= 8; off <<= 1) {
                s += __shfl_xor(s, off);
                sq += __shfl_xor(sq, off);
            }
            if (c == 0) {
                int q = 16 * m + 4 * g + reg;
                reds[q][w] = s;
                redq[q][w] = sq;
            }
        }
    }
    __syncthreads();
    #pragma unroll
    for (int m = 0; m < 4; m++) {
        #pragma unroll
        for (int reg = 0; reg < 4; reg++) {
            int q = 16 * m + 4 * g + reg;
            int r = row0 + q;
            float s = reds[q][0] + reds[q][1] + reds[q][2] + reds[q][3];
            float sq = redq[q][0] + redq[q][1] + redq[q][2] + redq[q][3];
            float mean = s * (1.f / 192.f);
            float var = sq * (1.f / 192.f) - mean * mean;
            float inv = rsqrtf(var + 1e-5f);
            if (r < NTOK) {
                #pragma unroll
                for (int n = 0; n < 3; n++) {
                    int col = 48 * w + 16 * n + c;
                    size_t idx = (size_t)r * C_DIM + col;
                    io[idx] = io[idx] + (acc[m][n][reg] - mean) * inv * g2[col] + b2[col];
                }
            }
        }
    }
}

extern "C" void kernel_launch(void* const* d_in, const int* in_sizes, int n_in,
                              void* d_out, int out_size, void* d_ws, size_t ws_size,
                              hipStream_t stream) {
    const float* x      = (const float*)d_in[0];
    const float* n1g    = (const float*)d_in[1];
    const float* n1b    = (const float*)d_in[2];
    const float* qkv_w  = (const float*)d_in[3];
    const float* qkv_b  = (const float*)d_in[4];
    const float* proj_w = (const float*)d_in[5];
    const float* proj_b = (const float*)d_in[6];
    const float* n2g    = (const float*)d_in[7];
    const float* n2b    = (const float*)d_in[8];
    const float* fc1_w  = (const float*)d_in[9];
    const float* fc1_b  = (const float*)d_in[10];
    const float* fc2_w  = (const float*)d_in[11];
    const float* fc2_b  = (const float*)d_in[12];
    float* out = (float*)d_out;

    if (ws_size < WS_REQUIRED) return;

    char* ws = (char*)d_ws;
    short* xw    = (short*)(ws);                 // MROWS*192 bf16, dead after qkv
    short* qkvb  = (short*)(ws + 53084160);      // MROWS*576 bf16, dead after attn
    short* attno = (short*)(ws);                 // MROWS*192 bf16 (reuse xw)
    short* hb    = (short*)(ws);                 // NTOK*768 bf16 (reuse)

    gather_ln_kernel<<<MROWS / 4, 256, 0, stream>>>(x, n1g, n1b, xw);

    gemm_mfma<0, false, 576><<<dim3(9, MROWS / 128), 256, 0, stream>>>(
        xw, qkv_w, qkv_b, qkvb, nullptr, nullptr, MROWS, 192);

    attn_mfma<<<NWIN * NH, 256, 0, stream>>>(qkvb, attno);

    gemm_mfma<1, false, 192><<<dim3(3, MROWS / 128), 256, 0, stream>>>(
        attno, proj_w, proj_b, nullptr, out, x, MROWS, 192);

    gemm_mfma<2, true, 768><<<dim3(12, (NTOK + 127) / 128), 256, 0, stream>>>(
        out, fc1_w, fc1_b, hb, nullptr, nullptr, NTOK, 192);

    fc2_ln_mfma<<<(NTOK + 63) / 64, 256, 0, stream>>>(
        hb, fc2_w, fc2_b, n2g, n2b, out);
}

// Round 4
// 559.592 us; speedup vs baseline: 6.1278x; 1.1954x over previous
//
#include <hip/hip_runtime.h>
#include <hip/hip_bf16.h>
#include <math.h>

#define C_DIM 192
#define NH 6
#define HD 32
#define L_WIN 144
#define NWIN 960
#define MROWS (NWIN * L_WIN)   // 138240 window rows
#define NTOK 131040            // 8*91*180 real tokens
#define Z_ 8
#define H_ 91
#define W_ 180
#define HP_ 96
#define WS_REQUIRED 212336640ull

// workspace offsets (bytes)
#define OFF_WBF   0ull                 // bf16 weights + beta, 885120 B
#define OFF_XWC   1048576ull           // bf16 NTOK*192 = 50,319,360
#define OFF_QKVB  51367936ull          // bf16 MROWS*576 = 159,252,480 (ends 210,620,416)
#define OFF_ATTNO 1048576ull           // reuse XWC after qkv
#define OFF_X1B   51367936ull          // reuse QKVB after attn
// wbf element offsets (shorts)
#define WO_QKV  0
#define WO_PROJ 110592
#define WO_FC1  147456
#define WO_FC2  294912
#define WO_BETA 442368
#define W_TOTAL 442560

typedef __attribute__((ext_vector_type(8))) short bf16x8;
typedef __attribute__((ext_vector_type(4))) float f32x4;

__device__ __forceinline__ short f2bf(float f) {
    union { __hip_bfloat16 h; short s; } u; u.h = __float2bfloat16(f); return u.s;
}
__device__ __forceinline__ float bf2f(short s) {
    return __uint_as_float(((unsigned int)(unsigned short)s) << 16);
}

__device__ __forceinline__ int win_token_to_tok(int r) {
    int n = r / L_WIN, l = r - n * L_WIN;
    int wz = n / 240;
    int rem = n - wz * 240;
    int wh = rem / 15;
    int ww = rem - wh * 15;
    int iz = l / 72;
    int r2 = l - iz * 72;
    int ih = r2 / 12;
    int iw = r2 - ih * 12;
    int z = wz * 2 + iz;
    int h = wh * 6 + ih;
    int w = ww * 12 + iw;
    int zp = z + 1; if (zp >= Z_) zp -= Z_;
    int hp = h + 3; if (hp >= HP_) hp -= HP_;
    int wp = w + 6; if (wp >= W_) wp -= W_;
    if (hp >= H_) return -1;
    return (zp * H_ + hp) * W_ + wp;
}

// ---------------- weight conversion: fp32 -> bf16 pool ------------------------
__global__ __launch_bounds__(256)
void wconv_kernel(const float* __restrict__ qw, const float* __restrict__ pw,
                  const float* __restrict__ f1w, const float* __restrict__ f2w,
                  const float* __restrict__ n1b, short* __restrict__ wbf) {
    int i = blockIdx.x * 256 + threadIdx.x;
    if (i >= W_TOTAL) return;
    float v;
    if (i < WO_PROJ)      v = qw[i];
    else if (i < WO_FC1)  v = pw[i - WO_PROJ];
    else if (i < WO_FC2)  v = f1w[i - WO_FC1];
    else if (i < WO_BETA) v = f2w[i - WO_FC2];
    else                  v = n1b[i - WO_BETA];
    wbf[i] = f2bf(v);
}

// ---------------- per-token LayerNorm(norm1) -> bf16 --------------------------
__global__ __launch_bounds__(256)
void ln_tok_kernel(const float* __restrict__ x, const float* __restrict__ g,
                   const float* __restrict__ b, short* __restrict__ xwc) {
    int wave = threadIdx.x >> 6, lane = threadIdx.x & 63;
    int r = blockIdx.x * 4 + wave;
    if (r >= NTOK) return;
    const float* p = x + (size_t)r * C_DIM;
    float v0 = p[lane], v1 = p[lane + 64], v2 = p[lane + 128];
    float s = v0 + v1 + v2;
    float sq = v0 * v0 + v1 * v1 + v2 * v2;
    #pragma unroll
    for (int off = 32; off; off >>= 1) {
        s += __shfl_xor(s, off);
        sq += __shfl_xor(sq, off);
    }
    float m = s * (1.f / 192.f);
    float var = sq * (1.f / 192.f) - m * m;
    float inv = rsqrtf(var + 1e-5f);
    short* o = xwc + (size_t)r * C_DIM;
    o[lane]       = f2bf((v0 - m) * inv * g[lane]       + b[lane]);
    o[lane + 64]  = f2bf((v1 - m) * inv * g[lane + 64]  + b[lane + 64]);
    o[lane + 128] = f2bf((v2 - m) * inv * g[lane + 128] + b[lane + 128]);
}

// ---------------- qkv GEMM: A staged once in LDS, B (bf16) from L2 ------------
// C[MROWS,576] = Awin[MROWS,192] @ qkv_wb[576,192]^T + qkv_b
// block: 128 rows x 64 cols; grid (9, 1080); A rows gathered via window map.
__global__ __launch_bounds__(256)
void qkv_gemm(const short* __restrict__ xwc, const short* __restrict__ wq,
              const short* __restrict__ beta, const float* __restrict__ bias,
              short* __restrict__ qkvb) {
    __shared__ __align__(16) short As[128][200];
    int t = threadIdx.x, w = t >> 6, l = t & 63, g = l >> 4, c = l & 15;
    int row0 = blockIdx.y * 128, col0 = blockIdx.x * 64;
    int wr = (w >> 1) * 64, wc = (w & 1) * 32;
    {
        int r = t & 127;
        int th = t >> 7;
        int tok = win_token_to_tok(row0 + r);
        const short* src = (tok >= 0) ? xwc + (size_t)tok * C_DIM : beta;
        #pragma unroll
        for (int i = 0; i < 12; i++) {
            int cidx = th + 2 * i;
            *(bf16x8*)(&As[r][cidx * 8]) = *(const bf16x8*)(src + cidx * 8);
        }
    }
    __syncthreads();
    f32x4 acc[4][2] = {};
    #pragma unroll
    for (int k0 = 0; k0 < 192; k0 += 32) {
        bf16x8 af[4], bfr[2];
        #pragma unroll
        for (int n = 0; n < 2; n++)
            bfr[n] = *(const bf16x8*)(wq + (size_t)(col0 + wc + 16 * n + c) * 192 + k0 + g * 8);
        #pragma unroll
        for (int m = 0; m < 4; m++) af[m] = *(const bf16x8*)(&As[wr + 16 * m + c][k0 + g * 8]);
        #pragma unroll
        for (int m = 0; m < 4; m++)
            #pragma unroll
            for (int n = 0; n < 2; n++)
                acc[m][n] = __builtin_amdgcn_mfma_f32_16x16x32_bf16(af[m], bfr[n], acc[m][n], 0, 0, 0);
    }
    #pragma unroll
    for (int m = 0; m < 4; m++)
        #pragma unroll
        for (int reg = 0; reg < 4; reg++) {
            int r = row0 + wr + 16 * m + 4 * g + reg;
            #pragma unroll
            for (int n = 0; n < 2; n++) {
                int col = col0 + wc + 16 * n + c;
                qkvb[(size_t)r * 576 + col] = f2bf(acc[m][n][reg] + bias[col]);
            }
        }
}

// ---------------- MFMA attention (unchanged core; token-compacted output) -----
__global__ __launch_bounds__(256)
void attn_mfma(const short* __restrict__ qkv, short* __restrict__ attno) {
    __shared__ __align__(16) short Vt[32][168];
    __shared__ __align__(16) short Pl[4][16][168];
    int blk = blockIdx.x;
    int win = blk / NH, head = blk - win * NH;
    int t = threadIdx.x, w = t >> 6, l = t & 63, g = l >> 4, c = l & 15;
    const short* base = qkv + (size_t)win * L_WIN * 576 + head * HD;

    for (int ch = t; ch < 576; ch += 256) {
        int kv = ch >> 2, cc = (ch & 3) * 8;
        bf16x8 v = *(const bf16x8*)(base + kv * 576 + 384 + cc);
        #pragma unroll
        for (int j = 0; j < 8; j++) Vt[cc + j][kv] = v[j];
    }
    for (int i = t; i < 32 * 24; i += 256) Vt[i / 24][144 + i % 24] = 0;
    for (int i = l; i < 16 * 24; i += 64) Pl[w][i / 24][144 + i % 24] = 0;
    __syncthreads();

    bf16x8 kf[9];
    #pragma unroll
    for (int n = 0; n < 9; n++)
        kf[n] = *(const bf16x8*)(base + (16 * n + c) * 576 + 192 + g * 8);

    const float scale = 0.17677669529663687f;
    for (int m = w; m < 9; m += 4) {
        bf16x8 qf = *(const bf16x8*)(base + (16 * m + c) * 576 + g * 8);
        f32x4 s[9];
        #pragma unroll
        for (int n = 0; n < 9; n++) {
            f32x4 z = {};
            s[n] = __builtin_amdgcn_mfma_f32_16x16x32_bf16(qf, kf[n], z, 0, 0, 0);
        }
        float mx[4], rs[4];
        #pragma unroll
        for (int reg = 0; reg < 4; reg++) {
            float v = -1e30f;
            #pragma unroll
            for (int n = 0; n < 9; n++) { s[n][reg] *= scale; v = fmaxf(v, s[n][reg]); }
            #pragma unroll
            for (int off = 1; off <= 8; off <<= 1) v = fmaxf(v, __shfl_xor(v, off));
            mx[reg] = v;
        }
        #pragma unroll
        for (int reg = 0; reg < 4; reg++) {
            float acc = 0.f;
            #pragma unroll
            for (int n = 0; n < 9; n++) {
                float e = __expf(s[n][reg] - mx[reg]);
                s[n][reg] = e;
                acc += e;
            }
            #pragma unroll
            for (int off = 1; off <= 8; off <<= 1) acc += __shfl_xor(acc, off);
            rs[reg] = 1.f / acc;
        }
        #pragma unroll
        for (int n = 0; n < 9; n++)
            #pragma unroll
            for (int reg = 0; reg < 4; reg++)
                Pl[w][4 * g + reg][16 * n + c] = f2bf(s[n][reg]);
        asm volatile("s_waitcnt lgkmcnt(0)" ::: "memory");
        f32x4 o[2] = {};
        #pragma unroll
        for (int ks = 0; ks < 5; ks++) {
            bf16x8 pa = *(const bf16x8*)(&Pl[w][c][32 * ks + 8 * g]);
            #pragma unroll
            for (int df = 0; df < 2; df++) {
                bf16x8 vb = *(const bf16x8*)(&Vt[16 * df + c][32 * ks + 8 * g]);
                o[df] = __builtin_amdgcn_mfma_f32_16x16x32_bf16(pa, vb, o[df], 0, 0, 0);
            }
        }
        #pragma unroll
        for (int reg = 0; reg < 4; reg++) {
            int grow = win * L_WIN + 16 * m + 4 * g + reg;
            int tok = win_token_to_tok(grow);
            if (tok < 0) continue;
            #pragma unroll
            for (int df = 0; df < 2; df++)
                attno[(size_t)tok * C_DIM + head * HD + 16 * df + c] =
                    f2bf(o[df][reg] * rs[reg]);
        }
    }
}

// ---------------- proj GEMM + residual -> x1 (bf16) ---------------------------
// x1b[r] = bf16( attno[r] @ proj_wb^T + proj_b + x[r] ), r = token
__global__ __launch_bounds__(256)
void proj_gemm(const short* __restrict__ attno, const short* __restrict__ wp,
               const float* __restrict__ bias, const float* __restrict__ x,
               short* __restrict__ x1b) {
    __shared__ __align__(16) short As[128][200];
    int t = threadIdx.x, w = t >> 6, l = t & 63, g = l >> 4, c = l & 15;
    int row0 = blockIdx.y * 128, col0 = blockIdx.x * 64;
    int wr = (w >> 1) * 64, wc = (w & 1) * 32;
    {
        int r = t & 127;
        int th = t >> 7;
        int gr = row0 + r;
        #pragma unroll
        for (int i = 0; i < 12; i++) {
            int cidx = th + 2 * i;
            bf16x8 v = {};
            if (gr < NTOK) v = *(const bf16x8*)(attno + (size_t)gr * C_DIM + cidx * 8);
            *(bf16x8*)(&As[r][cidx * 8]) = v;
        }
    }
    __syncthreads();
    f32x4 acc[4][2] = {};
    #pragma unroll
    for (int k0 = 0; k0 < 192; k0 += 32) {
        bf16x8 af[4], bfr[2];
        #pragma unroll
        for (int n = 0; n < 2; n++)
            bfr[n] = *(const bf16x8*)(wp + (size_t)(col0 + wc + 16 * n + c) * 192 + k0 + g * 8);
        #pragma unroll
        for (int m = 0; m < 4; m++) af[m] = *(const bf16x8*)(&As[wr + 16 * m + c][k0 + g * 8]);
        #pragma unroll
        for (int m = 0; m < 4; m++)
            #pragma unroll
            for (int n = 0; n < 2; n++)
                acc[m][n] = __builtin_amdgcn_mfma_f32_16x16x32_bf16(af[m], bfr[n], acc[m][n], 0, 0, 0);
    }
    #pragma unroll
    for (int m = 0; m < 4; m++)
        #pragma unroll
        for (int reg = 0; reg < 4; reg++) {
            int r = row0 + wr + 16 * m + 4 * g + reg;
            if (r >= NTOK) continue;
            #pragma unroll
            for (int n = 0; n < 2; n++) {
                int col = col0 + wc + 16 * n + c;
                float v = acc[m][n][reg] + bias[col] + x[(size_t)r * C_DIM + col];
                x1b[(size_t)r * C_DIM + col] = f2bf(v);
            }
        }
}

// ---------------- fused MLP: fc1+gelu+fc2+bias+LN(norm2)+residual -------------
// block: 64 rows; h computed in 4 quarters of 192 cols, staged in LDS.
__global__ __launch_bounds__(256)
void mlp_kernel(const short* __restrict__ x1b, const short* __restrict__ w1,
                const short* __restrict__ w2, const float* __restrict__ b1,
                const float* __restrict__ b2, const float* __restrict__ g2,
                const float* __restrict__ bb2, float* __restrict__ out) {
    __shared__ __align__(16) short As[64][200];
    __shared__ __align__(16) short Hs[64][200];
    __shared__ float red_s[64][4];
    __shared__ float red_q[64][4];
    int t = threadIdx.x, w = t >> 6, l = t & 63, g = l >> 4, c = l & 15;
    int row0 = blockIdx.x * 64;
    {
        int r = t & 63;
        int sg = t >> 6;
        int gr = row0 + r;
        #pragma unroll
        for (int i = 0; i < 6; i++) {
            int cidx = sg + 4 * i;
            bf16x8 v = {};
            if (gr < NTOK) v = *(const bf16x8*)(x1b + (size_t)gr * C_DIM + cidx * 8);
            *(bf16x8*)(&As[r][cidx * 8]) = v;
        }
    }
    __syncthreads();

    f32x4 acc2[4][3] = {};
    for (int q = 0; q < 4; q++) {
        f32x4 acc1[4][3] = {};
        #pragma unroll
        for (int k0 = 0; k0 < 192; k0 += 32) {
            bf16x8 af[4], bfr[3];
            #pragma unroll
            for (int n = 0; n < 3; n++)
                bfr[n] = *(const bf16x8*)(w1 + (size_t)(q * 192 + 48 * w + 16 * n + c) * 192 + k0 + g * 8);
            #pragma unroll
            for (int m = 0; m < 4; m++) af[m] = *(const bf16x8*)(&As[16 * m + c][k0 + g * 8]);
            #pragma unroll
            for (int m = 0; m < 4; m++)
                #pragma unroll
                for (int n = 0; n < 3; n++)
                    acc1[m][n] = __builtin_amdgcn_mfma_f32_16x16x32_bf16(af[m], bfr[n], acc1[m][n], 0, 0, 0);
        }
        // GELU (tanh/sigmoid form) -> Hs
        #pragma unroll
        for (int m = 0; m < 4; m++)
            #pragma unroll
            for (int n = 0; n < 3; n++)
                #pragma unroll
                for (int reg = 0; reg < 4; reg++) {
                    int col = 48 * w + 16 * n + c;
                    float v = acc1[m][n][reg] + b1[q * 192 + col];
                    float u = v * (1.5957691216f + 0.0713548162f * v * v);
                    float e = exp2f(-1.4426950409f * u);
                    float gl = v * __builtin_amdgcn_rcpf(1.f + e);
                    Hs[16 * m + 4 * g + reg][col] = f2bf(gl);
                }
        __syncthreads();
        #pragma unroll
        for (int k0 = 0; k0 < 192; k0 += 32) {
            bf16x8 pa[4], bfr[3];
            #pragma unroll
            for (int n = 0; n < 3; n++)
                bfr[n] = *(const bf16x8*)(w2 + (size_t)(48 * w + 16 * n + c) * 768 + q * 192 + k0 + g * 8);
            #pragma unroll
            for (int m = 0; m < 4; m++) pa[m] = *(const bf16x8*)(&Hs[16 * m + c][k0 + g * 8]);
            #pragma unroll
            for (int m = 0; m < 4; m++)
                #pragma unroll
                for (int n = 0; n < 3; n++)
                    acc2[m][n] = __builtin_amdgcn_mfma_f32_16x16x32_bf16(pa[m], bfr[n], acc2[m][n], 0, 0, 0);
        }
        __syncthreads();
    }

    // bias + row stats
    #pragma unroll
    for (int m = 0; m < 4; m++)
        #pragma unroll
        for (int reg = 0; reg < 4; reg++) {
            float s = 0.f, sq = 0.f;
            #pragma unroll
            for (int n = 0; n < 3; n++) {
                int col = 48 * w + 16 * n + c;
                float h = acc2[m][n][reg] + b2[col];
                acc2[m][n][reg] = h;
                s += h; sq += h * h;
            }
            #pragma unroll
            for (int off = 1; off <= 8; off <<= 1) {
                s += __shfl_xor(s, off);
                sq += __shfl_xor(sq, off);
            }
            if (c == 0) {
                int q16 = 16 * m + 4 * g + reg;
                red_s[q16][w] = s;
                red_q[q16][w] = sq;
            }
        }
    __syncthreads();
    #pragma unroll
    for (int m = 0; m < 4; m++)
        #pragma unroll
        for (int reg = 0; reg < 4; reg++) {
            int q16 = 16 * m + 4 * g + reg;
            int r = row0 + q16;
            float s = red_s[q16][0] + red_s[q16][1] + red_s[q16][2] + red_s[q16][3];
            float sq = red_q[q16][0] + red_q[q16][1] + red_q[q16][2] + red_q[q16][3];
            float mean = s * (1.f / 192.f);
            float var = sq * (1.f / 192.f) - mean * mean;
            float inv = rsqrtf(var + 1e-5f);
            if (r < NTOK) {
                #pragma unroll
                for (int n = 0; n < 3; n++) {
                    int col = 48 * w + 16 * n + c;
                    out[(size_t)r * C_DIM + col] =
                        bf2f(As[q16][col]) + (acc2[m][n][reg] - mean) * inv * g2[col] + bb2[col];
                }
            }
        }
}

extern "C" void kernel_launch(void* const* d_in, const int* in_sizes, int n_in,
                              void* d_out, int out_size, void* d_ws, size_t ws_size,
                              hipStream_t stream) {
    const float* x      = (const float*)d_in[0];
    const float* n1g    = (const float*)d_in[1];
    const float* n1b    = (const float*)d_in[2];
    const float* qkv_w  = (const float*)d_in[3];
    const float* qkv_b  = (const float*)d_in[4];
    const float* proj_w = (const float*)d_in[5];
    const float* proj_b = (const float*)d_in[6];
    const float* n2g    = (const float*)d_in[7];
    const float* n2b    = (const float*)d_in[8];
    const float* fc1_w  = (const float*)d_in[9];
    const float* fc1_b  = (const float*)d_in[10];
    const float* fc2_w  = (const float*)d_in[11];
    const float* fc2_b  = (const float*)d_in[12];
    float* out = (float*)d_out;

    if (ws_size < WS_REQUIRED) return;

    char* ws = (char*)d_ws;
    short* wbf   = (short*)(ws + OFF_WBF);
    short* xwc   = (short*)(ws + OFF_XWC);
    short* qkvb  = (short*)(ws + OFF_QKVB);
    short* attno = (short*)(ws + OFF_ATTNO);
    short* x1b   = (short*)(ws + OFF_X1B);

    wconv_kernel<<<(W_TOTAL + 255) / 256, 256, 0, stream>>>(
        qkv_w, proj_w, fc1_w, fc2_w, n1b, wbf);

    ln_tok_kernel<<<NTOK / 4, 256, 0, stream>>>(x, n1g, n1b, xwc);

    qkv_gemm<<<dim3(9, MROWS / 128), 256, 0, stream>>>(
        xwc, wbf + WO_QKV, wbf + WO_BETA, qkv_b, qkvb);

    attn_mfma<<<NWIN * NH, 256, 0, stream>>>(qkvb, attno);

    proj_gemm<<<dim3(3, (NTOK + 127) / 128), 256, 0, stream>>>(
        attno, wbf + WO_PROJ, proj_b, x, x1b);

    mlp_kernel<<<(NTOK + 63) / 64, 256, 0, stream>>>(
        x1b, wbf + WO_FC1, wbf + WO_FC2, fc1_b, fc2_b, n2g, n2b, out);
}

// Round 6
// 521.118 us; speedup vs baseline: 6.5802x; 1.0738x over previous
//
#include <hip/hip_runtime.h>
#include <hip/hip_bf16.h>
#include <math.h>

#define C_DIM 192
#define NH 6
#define HD 32
#define L_WIN 144
#define NWIN 960
#define MROWS (NWIN * L_WIN)   // 138240 window rows
#define NTOK 131040            // 8*91*180 real tokens
#define Z_ 8
#define H_ 91
#define W_ 180
#define HP_ 96
#define WS_REQUIRED 212336640ull

// workspace offsets (bytes)
#define OFF_WBF   0ull                 // bf16 weights + beta
#define OFF_XWC   1048576ull           // bf16 NTOK*192
#define OFF_QKVB  51367936ull          // bf16 MROWS*576 (ends 210,620,416)
#define OFF_ATTNO 1048576ull           // reuse XWC after qkv
#define OFF_X1B   51367936ull          // reuse QKVB after attn
// wbf element offsets (shorts)
#define WO_QKV  0
#define WO_PROJ 110592
#define WO_FC1  147456
#define WO_FC2  294912
#define WO_BETA 442368
#define W_TOTAL 442560

typedef __attribute__((ext_vector_type(8))) short bf16x8;
typedef __attribute__((ext_vector_type(4))) short s16x4;
typedef __attribute__((ext_vector_type(4))) float f32x4;

__device__ __forceinline__ short f2bf(float f) {
    union { __hip_bfloat16 h; short s; } u; u.h = __float2bfloat16(f); return u.s;
}
__device__ __forceinline__ float bf2f(short s) {
    return __uint_as_float(((unsigned int)(unsigned short)s) << 16);
}

__device__ __forceinline__ int win_token_to_tok(int r) {
    int n = r / L_WIN, l = r - n * L_WIN;
    int wz = n / 240;
    int rem = n - wz * 240;
    int wh = rem / 15;
    int ww = rem - wh * 15;
    int iz = l / 72;
    int r2 = l - iz * 72;
    int ih = r2 / 12;
    int iw = r2 - ih * 12;
    int z = wz * 2 + iz;
    int h = wh * 6 + ih;
    int w = ww * 12 + iw;
    int zp = z + 1; if (zp >= Z_) zp -= Z_;
    int hp = h + 3; if (hp >= HP_) hp -= HP_;
    int wp = w + 6; if (wp >= W_) wp -= W_;
    if (hp >= H_) return -1;
    return (zp * H_ + hp) * W_ + wp;
}

// ---------------- weight conversion: fp32 -> bf16 pool ------------------------
__global__ __launch_bounds__(256)
void wconv_kernel(const float* __restrict__ qw, const float* __restrict__ pw,
                  const float* __restrict__ f1w, const float* __restrict__ f2w,
                  const float* __restrict__ n1b, short* __restrict__ wbf) {
    int i = blockIdx.x * 256 + threadIdx.x;
    if (i >= W_TOTAL) return;
    float v;
    if (i < WO_PROJ)      v = qw[i];
    else if (i < WO_FC1)  v = pw[i - WO_PROJ];
    else if (i < WO_FC2)  v = f1w[i - WO_FC1];
    else if (i < WO_BETA) v = f2w[i - WO_FC2];
    else                  v = n1b[i - WO_BETA];
    wbf[i] = f2bf(v);
}

// ---------------- per-token LayerNorm(norm1) -> bf16 --------------------------
__global__ __launch_bounds__(256)
void ln_tok_kernel(const float* __restrict__ x, const float* __restrict__ g,
                   const float* __restrict__ b, short* __restrict__ xwc) {
    int wave = threadIdx.x >> 6, lane = threadIdx.x & 63;
    int r = blockIdx.x * 4 + wave;
    if (r >= NTOK) return;
    const float* p = x + (size_t)r * C_DIM;
    float v0 = p[lane], v1 = p[lane + 64], v2 = p[lane + 128];
    float s = v0 + v1 + v2;
    float sq = v0 * v0 + v1 * v1 + v2 * v2;
    #pragma unroll
    for (int off = 32; off; off >>= 1) {
        s += __shfl_xor(s, off);
        sq += __shfl_xor(sq, off);
    }
    float m = s * (1.f / 192.f);
    float var = sq * (1.f / 192.f) - m * m;
    float inv = rsqrtf(var + 1e-5f);
    short* o = xwc + (size_t)r * C_DIM;
    o[lane]       = f2bf((v0 - m) * inv * g[lane]       + b[lane]);
    o[lane + 64]  = f2bf((v1 - m) * inv * g[lane + 64]  + b[lane + 64]);
    o[lane + 128] = f2bf((v2 - m) * inv * g[lane + 128] + b[lane + 128]);
}

// ---------------- qkv GEMM -> layout [win][head][{q,k,v}][144][32] ------------
__global__ __launch_bounds__(256)
void qkv_gemm(const short* __restrict__ xwc, const short* __restrict__ wq,
              const short* __restrict__ beta, const float* __restrict__ bias,
              short* __restrict__ qkvb) {
    __shared__ __align__(16) short As[128][200];
    int t = threadIdx.x, w = t >> 6, l = t & 63, g = l >> 4, c = l & 15;
    // XCD swizzle: the 9 col-tiles sharing an A-tile land on one XCD
    int bid = blockIdx.x + 9 * blockIdx.y;
    int xcd = bid & 7, sq_ = bid >> 3;
    int bx = sq_ % 9, by = xcd + 8 * (sq_ / 9);
    int row0 = by * 128, col0 = bx * 64;
    int wr = (w >> 1) * 64, wc = (w & 1) * 32;
    {
        int r = t & 127;
        int th = t >> 7;
        int tok = win_token_to_tok(row0 + r);
        const short* src = (tok >= 0) ? xwc + (size_t)tok * C_DIM : beta;
        #pragma unroll
        for (int i = 0; i < 12; i++) {
            int cidx = th + 2 * i;
            *(bf16x8*)(&As[r][cidx * 8]) = *(const bf16x8*)(src + cidx * 8);
        }
    }
    __syncthreads();
    f32x4 acc[4][2] = {};
    const short* wqb = wq + (size_t)(col0 + wc + c) * 192 + g * 8;
    bf16x8 cur[2], nxt[2];
    #pragma unroll
    for (int n = 0; n < 2; n++) cur[n] = *(const bf16x8*)(wqb + n * 3072);
    #pragma unroll
    for (int ks = 0; ks < 6; ks++) {
        if (ks < 5) {
            #pragma unroll
            for (int n = 0; n < 2; n++)
                nxt[n] = *(const bf16x8*)(wqb + n * 3072 + (ks + 1) * 32);
        }
        bf16x8 af[4];
        #pragma unroll
        for (int m = 0; m < 4; m++)
            af[m] = *(const bf16x8*)(&As[wr + 16 * m + c][ks * 32 + g * 8]);
        #pragma unroll
        for (int m = 0; m < 4; m++)
            #pragma unroll
            for (int n = 0; n < 2; n++)
                acc[m][n] = __builtin_amdgcn_mfma_f32_16x16x32_bf16(af[m], cur[n], acc[m][n], 0, 0, 0);
        if (ks < 5) {
            #pragma unroll
            for (int n = 0; n < 2; n++) cur[n] = nxt[n];
        }
    }
    #pragma unroll
    for (int m = 0; m < 4; m++)
        #pragma unroll
        for (int reg = 0; reg < 4; reg++) {
            int r = row0 + wr + 16 * m + 4 * g + reg;
            int win = r / 144, ll = r - win * 144;
            #pragma unroll
            for (int n = 0; n < 2; n++) {
                int col = col0 + wc + 16 * n + c;
                int sec = col / 192;
                int head = (col - sec * 192) >> 5;
                int d = col & 31;
                size_t dst = ((size_t)(win * 6 + head) * 3 + sec) * 4608 + ll * 32 + d;
                qkvb[dst] = f2bf(acc[m][n][reg] + bias[col]);
            }
        }
}

// ---------------- MFMA attention: 192 threads, 3 waves x 3 m-frags ------------
__global__ __launch_bounds__(192)
void attn_mfma(const short* __restrict__ qkvb, short* __restrict__ attno) {
    __shared__ __align__(16) short Vt[32][168];
    __shared__ __align__(16) short Pl[3][16][168];
    int blk = blockIdx.x;
    int win = blk / NH, head = blk - win * NH;
    int t = threadIdx.x, w = t >> 6, l = t & 63, g = l >> 4, c = l & 15;
    const short* qb = qkvb + (size_t)(win * 6 + head) * 13824;
    const short* kb = qb + 4608;
    const short* vb = qb + 9216;
    for (int ch = t; ch < 576; ch += 192) {
        int kv = ch >> 2, cc = (ch & 3) * 8;
        bf16x8 v = *(const bf16x8*)(vb + kv * 32 + cc);
        #pragma unroll
        for (int j = 0; j < 8; j++) Vt[cc + j][kv] = v[j];
    }
    for (int i = t; i < 32 * 24; i += 192) Vt[i / 24][144 + i % 24] = 0;
    for (int i = l; i < 16 * 24; i += 64) Pl[w][i / 24][144 + i % 24] = 0;
    __syncthreads();

    bf16x8 kf[9];
    #pragma unroll
    for (int n = 0; n < 9; n++)
        kf[n] = *(const bf16x8*)(kb + (16 * n + c) * 32 + g * 8);

    const float scale2 = 0.2550348668f;  // (1/sqrt(32)) * log2(e)
    for (int m = w; m < 9; m += 3) {
        bf16x8 qf = *(const bf16x8*)(qb + (16 * m + c) * 32 + g * 8);
        f32x4 sv[9];
        #pragma unroll
        for (int n = 0; n < 9; n++) {
            f32x4 z = {};
            sv[n] = __builtin_amdgcn_mfma_f32_16x16x32_bf16(qf, kf[n], z, 0, 0, 0);
        }
        float mx[4], rs[4];
        #pragma unroll
        for (int reg = 0; reg < 4; reg++) {
            float v = -1e30f;
            #pragma unroll
            for (int n = 0; n < 9; n++) { sv[n][reg] *= scale2; v = fmaxf(v, sv[n][reg]); }
            #pragma unroll
            for (int off = 1; off <= 8; off <<= 1) v = fmaxf(v, __shfl_xor(v, off));
            mx[reg] = v;
        }
        #pragma unroll
        for (int reg = 0; reg < 4; reg++) {
            float acc = 0.f;
            #pragma unroll
            for (int n = 0; n < 9; n++) {
                float e = exp2f(sv[n][reg] - mx[reg]);
                sv[n][reg] = e;
                acc += e;
            }
            #pragma unroll
            for (int off = 1; off <= 8; off <<= 1) acc += __shfl_xor(acc, off);
            rs[reg] = 1.f / acc;
        }
        #pragma unroll
        for (int n = 0; n < 9; n++)
            #pragma unroll
            for (int reg = 0; reg < 4; reg++)
                Pl[w][4 * g + reg][16 * n + c] = f2bf(sv[n][reg]);
        asm volatile("s_waitcnt lgkmcnt(0)" ::: "memory");
        f32x4 o[2] = {};
        #pragma unroll
        for (int ks = 0; ks < 5; ks++) {
            bf16x8 pa = *(const bf16x8*)(&Pl[w][c][32 * ks + 8 * g]);
            #pragma unroll
            for (int df = 0; df < 2; df++) {
                bf16x8 vv = *(const bf16x8*)(&Vt[16 * df + c][32 * ks + 8 * g]);
                o[df] = __builtin_amdgcn_mfma_f32_16x16x32_bf16(pa, vv, o[df], 0, 0, 0);
            }
        }
        #pragma unroll
        for (int reg = 0; reg < 4; reg++) {
            int grow = win * L_WIN + 16 * m + 4 * g + reg;
            int tok = win_token_to_tok(grow);
            if (tok < 0) continue;
            #pragma unroll
            for (int df = 0; df < 2; df++)
                attno[(size_t)tok * C_DIM + head * HD + 16 * df + c] =
                    f2bf(o[df][reg] * rs[reg]);
        }
    }
}

// ---------------- proj GEMM + residual -> x1 (bf16) ---------------------------
__global__ __launch_bounds__(256)
void proj_gemm(const short* __restrict__ attno, const short* __restrict__ wp,
               const float* __restrict__ bias, const float* __restrict__ x,
               short* __restrict__ x1b) {
    __shared__ __align__(16) short As[128][200];
    int t = threadIdx.x, w = t >> 6, l = t & 63, g = l >> 4, c = l & 15;
    int bid = blockIdx.x + 3 * blockIdx.y;
    int xcd = bid & 7, sq_ = bid >> 3;
    int bx = sq_ % 3, by = xcd + 8 * (sq_ / 3);
    int row0 = by * 128, col0 = bx * 64;
    int wr = (w >> 1) * 64, wc = (w & 1) * 32;
    {
        int r = t & 127;
        int th = t >> 7;
        int gr = row0 + r;
        #pragma unroll
        for (int i = 0; i < 12; i++) {
            int cidx = th + 2 * i;
            bf16x8 v = {};
            if (gr < NTOK) v = *(const bf16x8*)(attno + (size_t)gr * C_DIM + cidx * 8);
            *(bf16x8*)(&As[r][cidx * 8]) = v;
        }
    }
    __syncthreads();
    f32x4 acc[4][2] = {};
    const short* wpb = wp + (size_t)(col0 + wc + c) * 192 + g * 8;
    bf16x8 cur[2], nxt[2];
    #pragma unroll
    for (int n = 0; n < 2; n++) cur[n] = *(const bf16x8*)(wpb + n * 3072);
    #pragma unroll
    for (int ks = 0; ks < 6; ks++) {
        if (ks < 5) {
            #pragma unroll
            for (int n = 0; n < 2; n++)
                nxt[n] = *(const bf16x8*)(wpb + n * 3072 + (ks + 1) * 32);
        }
        bf16x8 af[4];
        #pragma unroll
        for (int m = 0; m < 4; m++)
            af[m] = *(const bf16x8*)(&As[wr + 16 * m + c][ks * 32 + g * 8]);
        #pragma unroll
        for (int m = 0; m < 4; m++)
            #pragma unroll
            for (int n = 0; n < 2; n++)
                acc[m][n] = __builtin_amdgcn_mfma_f32_16x16x32_bf16(af[m], cur[n], acc[m][n], 0, 0, 0);
        if (ks < 5) {
            #pragma unroll
            for (int n = 0; n < 2; n++) cur[n] = nxt[n];
        }
    }
    #pragma unroll
    for (int m = 0; m < 4; m++)
        #pragma unroll
        for (int reg = 0; reg < 4; reg++) {
            int r = row0 + wr + 16 * m + 4 * g + reg;
            if (r >= NTOK) continue;
            #pragma unroll
            for (int n = 0; n < 2; n++) {
                int col = col0 + wc + 16 * n + c;
                float v = acc[m][n][reg] + bias[col] + x[(size_t)r * C_DIM + col];
                x1b[(size_t)r * C_DIM + col] = f2bf(v);
            }
        }
}

// ---------------- fused MLP: fc1(swapped)+gelu+fc2+bias+LN(norm2)+residual ----
__global__ __launch_bounds__(256)
void mlp_kernel(const short* __restrict__ x1b, const short* __restrict__ w1,
                const short* __restrict__ w2, const float* __restrict__ b1,
                const float* __restrict__ b2, const float* __restrict__ g2,
                const float* __restrict__ bb2, float* __restrict__ out) {
    __shared__ __align__(16) short As[64][200];
    __shared__ __align__(16) short Hs[64][200];
    __shared__ float red_s[64][4];
    __shared__ float red_q[64][4];
    int t = threadIdx.x, w = t >> 6, l = t & 63, g = l >> 4, c = l & 15;
    int row0 = blockIdx.x * 64;
    {
        int r = t & 63, sg = t >> 6;
        int gr = row0 + r;
        #pragma unroll
        for (int i = 0; i < 6; i++) {
            int cidx = sg + 4 * i;
            bf16x8 v = {};
            if (gr < NTOK) v = *(const bf16x8*)(x1b + (size_t)gr * C_DIM + cidx * 8);
            *(bf16x8*)(&As[r][cidx * 8]) = v;
        }
    }
    __syncthreads();

    f32x4 acc2[4][3] = {};
    for (int q = 0; q < 4; q++) {
        // fc1 operand-swapped: rows = hidden (this wave's 48), cols = 64 tokens
        const short* w1b = w1 + (size_t)(q * 192 + 48 * w + c) * 192 + g * 8;
        f32x4 acc1[3][4] = {};
        bf16x8 cur1[3], nxt1[3];
        #pragma unroll
        for (int mh = 0; mh < 3; mh++) cur1[mh] = *(const bf16x8*)(w1b + mh * 3072);
        #pragma unroll
        for (int ks = 0; ks < 6; ks++) {
            if (ks < 5) {
                #pragma unroll
                for (int mh = 0; mh < 3; mh++)
                    nxt1[mh] = *(const bf16x8*)(w1b + mh * 3072 + (ks + 1) * 32);
            }
            bf16x8 bx[4];
            #pragma unroll
            for (int tn = 0; tn < 4; tn++)
                bx[tn] = *(const bf16x8*)(&As[16 * tn + c][ks * 32 + g * 8]);
            #pragma unroll
            for (int mh = 0; mh < 3; mh++)
                #pragma unroll
                for (int tn = 0; tn < 4; tn++)
                    acc1[mh][tn] = __builtin_amdgcn_mfma_f32_16x16x32_bf16(cur1[mh], bx[tn], acc1[mh][tn], 0, 0, 0);
            if (ks < 5) {
                #pragma unroll
                for (int mh = 0; mh < 3; mh++) cur1[mh] = nxt1[mh];
            }
        }
        // GELU into packed registers (4 consecutive hidden cols per lane)
        s16x4 pk[3][4];
        #pragma unroll
        for (int mh = 0; mh < 3; mh++) {
            float bv[4];
            #pragma unroll
            for (int reg = 0; reg < 4; reg++)
                bv[reg] = b1[q * 192 + 48 * w + 16 * mh + 4 * g + reg];
            #pragma unroll
            for (int tn = 0; tn < 4; tn++) {
                #pragma unroll
                for (int reg = 0; reg < 4; reg++) {
                    float v = acc1[mh][tn][reg] + bv[reg];
                    float u = v * (1.5957691216f + 0.0713548162f * v * v);
                    float e = exp2f(-1.4426950409f * u);
                    pk[mh][tn][reg] = f2bf(v * __builtin_amdgcn_rcpf(1.f + e));
                }
            }
        }
        __syncthreads();   // previous quarter's fc2 reads complete
        #pragma unroll
        for (int mh = 0; mh < 3; mh++)
            #pragma unroll
            for (int tn = 0; tn < 4; tn++)
                *(s16x4*)(&Hs[16 * tn + c][48 * w + 16 * mh + 4 * g]) = pk[mh][tn];
        __syncthreads();   // Hs visible to all waves
        // fc2 partial: acc2[tm][n] += H_q x W2_q
        const short* w2b = w2 + (size_t)(48 * w + c) * 768 + q * 192 + g * 8;
        bf16x8 cur2[3], nxt2[3];
        #pragma unroll
        for (int n = 0; n < 3; n++) cur2[n] = *(const bf16x8*)(w2b + n * 12288);
        #pragma unroll
        for (int ks = 0; ks < 6; ks++) {
            if (ks < 5) {
                #pragma unroll
                for (int n = 0; n < 3; n++)
                    nxt2[n] = *(const bf16x8*)(w2b + n * 12288 + (ks + 1) * 32);
            }
            bf16x8 pa[4];
            #pragma unroll
            for (int tm = 0; tm < 4; tm++)
                pa[tm] = *(const bf16x8*)(&Hs[16 * tm + c][ks * 32 + g * 8]);
            #pragma unroll
            for (int tm = 0; tm < 4; tm++)
                #pragma unroll
                for (int n = 0; n < 3; n++)
                    acc2[tm][n] = __builtin_amdgcn_mfma_f32_16x16x32_bf16(pa[tm], cur2[n], acc2[tm][n], 0, 0, 0);
            if (ks < 5) {
                #pragma unroll
                for (int n = 0; n < 3; n++) cur2[n] = nxt2[n];
            }
        }
    }

    // bias + row stats + LN + residual
    #pragma unroll
    for (int m = 0; m < 4; m++)
        #pragma unroll
        for (int reg = 0; reg < 4; reg++) {
            float s = 0.f, sq = 0.f;
            #pragma unroll
            for (int n = 0; n < 3; n++) {
                int col = 48 * w + 16 * n + c;
                float h = acc2[m][n][reg] + b2[col];
                acc2[m][n][reg] = h;
                s += h; sq += h * h;
            }
            #pragma unroll
            for (int off = 1; off <= 8; off <<= 1) {
                s += __shfl_xor(s, off);
                sq += __shfl_xor(sq, off);
            }
            if (c == 0) {
                int q16 = 16 * m + 4 * g + reg;
                red_s[q16][w] = s;
                red_q[q16][w] = sq;
            }
        }
    __syncthreads();
    #pragma unroll
    for (int m = 0; m < 4; m++)
        #pragma unroll
        for (int reg = 0; reg < 4; reg++) {
            int q16 = 16 * m + 4 * g + reg;
            int r = row0 + q16;
            float s = red_s[q16][0] + red_s[q16][1] + red_s[q16][2] + red_s[q16][3];
            float sq = red_q[q16][0] + red_q[q16][1] + red_q[q16][2] + red_q[q16][3];
            float mean = s * (1.f / 192.f);
            float var = sq * (1.f / 192.f) - mean * mean;
            float inv = rsqrtf(var + 1e-5f);
            if (r < NTOK) {
                #pragma unroll
                for (int n = 0; n < 3; n++) {
                    int col = 48 * w + 16 * n + c;
                    out[(size_t)r * C_DIM + col] =
                        bf2f(As[q16][col]) + (acc2[m][n][reg] - mean) * inv * g2[col] + bb2[col];
                }
            }
        }
}

extern "C" void kernel_launch(void* const* d_in, const int* in_sizes, int n_in,
                              void* d_out, int out_size, void* d_ws, size_t ws_size,
                              hipStream_t stream) {
    const float* x      = (const float*)d_in[0];
    const float* n1g    = (const float*)d_in[1];
    const float* n1b    = (const float*)d_in[2];
    const float* qkv_w  = (const float*)d_in[3];
    const float* qkv_b  = (const float*)d_in[4];
    const float* proj_w = (const float*)d_in[5];
    const float* proj_b = (const float*)d_in[6];
    const float* n2g    = (const float*)d_in[7];
    const float* n2b    = (const float*)d_in[8];
    const float* fc1_w  = (const float*)d_in[9];
    const float* fc1_b_ = (const float*)d_in[10];
    const float* fc2_w  = (const float*)d_in[11];
    const float* fc2_b  = (const float*)d_in[12];
    float* out = (float*)d_out;

    if (ws_size < WS_REQUIRED) return;

    char* ws = (char*)d_ws;
    short* wbf   = (short*)(ws + OFF_WBF);
    short* xwc   = (short*)(ws + OFF_XWC);
    short* qkvb  = (short*)(ws + OFF_QKVB);
    short* attno = (short*)(ws + OFF_ATTNO);
    short* x1b   = (short*)(ws + OFF_X1B);

    wconv_kernel<<<(W_TOTAL + 255) / 256, 256, 0, stream>>>(
        qkv_w, proj_w, fc1_w, fc2_w, n1b, wbf);

    ln_tok_kernel<<<NTOK / 4, 256, 0, stream>>>(x, n1g, n1b, xwc);

    qkv_gemm<<<dim3(9, MROWS / 128), 256, 0, stream>>>(
        xwc, wbf + WO_QKV, wbf + WO_BETA, qkv_b, qkvb);

    attn_mfma<<<NWIN * NH, 192, 0, stream>>>(qkvb, attno);

    proj_gemm<<<dim3(3, (NTOK + 127) / 128), 256, 0, stream>>>(
        attno, wbf + WO_PROJ, proj_b, x, x1b);

    mlp_kernel<<<(NTOK + 63) / 64, 256, 0, stream>>>(
        x1b, wbf + WO_FC1, wbf + WO_FC2, fc1_b_, fc2_b, n2g, n2b, out);
}